// Round 16
// baseline (53.486 us; speedup 1.0000x reference)
//
#include <hip/hip_runtime.h>
#include <hip/hip_bf16.h>
#include <hip/hip_fp16.h>
#include <math.h>

#define NG  256
#define NN  64
#define KK  24
#define HID 128
#define KP  136   // bf16 LDS row stride (shorts): 272B
#define VP  136   // f16 V row stride (shorts): 272B
#define DP  68    // dmat row stride (floats)
#define FRAG 512                 // shorts per fragment (64 lanes x 8)
#define SLAB (8*4*2*FRAG)        // 32768 shorts per full hi/lo weight slab (64KB)
#define HSLAB (8*4*FRAG)         // 16384 shorts per hi-only compact slab (32KB)
#define IMG_BYTES (3*SLAB*2)     // 196608 B

typedef __attribute__((ext_vector_type(8)))  short bf16x8;
typedef __attribute__((ext_vector_type(4)))  float f32x4;

__device__ __forceinline__ float elu1(float x){ return x > 0.f ? x : (__expf(x)-1.f); }

// truncation-based bf16 split
__device__ __forceinline__ short bf_t(float x){ return (short)(__float_as_uint(x) >> 16); }
__device__ __forceinline__ float bf_u(short s){ return __uint_as_float(((unsigned)(unsigned short)s) << 16); }

__device__ __forceinline__ short f2h(float x){ __half h = __float2half(x); return *(short*)&h; }
__device__ __forceinline__ unsigned pkmax(unsigned a, unsigned b){
    unsigned r; asm("v_pk_max_f16 %0, %1, %2" : "=v"(r) : "v"(a), "v"(b)); return r;
}
__device__ __forceinline__ float2 h22f2(unsigned u){
    __half2 h = *(__half2*)&u; return __half22float2(h);
}

// ---- prep: weights -> 16x16-MFMA-fragment-ordered bf16 hi/lo images ----
extern "C" __global__ void prep_kernel(const float* __restrict__ W2,
                                       const float* __restrict__ Wc,
                                       short* __restrict__ img)
{
    int t = blockIdx.x * 256 + threadIdx.x;    // (s,tn,ks,lane)
    if (t >= 3*8*4*64) return;
    const int lane = t & 63;
    const int ks   = (t >> 6) & 3;
    const int tn   = (t >> 8) & 7;
    const int s    = t >> 11;
    const int n     = tn*16 + (lane & 15);
    const int kbase = ks*32 + (lane >> 4)*8;
    bf16x8 hv, lv;
    #pragma unroll
    for (int j = 0; j < 8; ++j){
        const int k = kbase + j;
        float w = (s == 0) ? W2[k*HID + n]
                : (s == 1) ? Wc[k*HID + n]
                           : Wc[(k + HID)*HID + n];
        short h = bf_t(w);
        hv[j] = h;
        lv[j] = bf_t(w - bf_u(h));
    }
    short* dst = img + s*SLAB + ((tn*4 + ks)*2)*FRAG + lane*8;
    *(bf16x8*)(dst)        = hv;
    *(bf16x8*)(dst + FRAG) = lv;
}

__device__ __forceinline__ void stage_copy(const short* __restrict__ src,
                                           short* __restrict__ slab, int tid)
{
    const uint4* s = (const uint4*)src;
    uint4* d = (uint4*)slab;
    #pragma unroll
    for (int i = 0; i < 4; ++i) d[tid + i*1024] = s[tid + i*1024];
}

__device__ __forceinline__ void stage_build(const float* __restrict__ Wg, int rowoff,
                                            short* __restrict__ slab, int tid)
{
    for (int i = tid; i < 8*4*64; i += 1024){
        const int lane2 = i & 63;
        const int ks    = (i >> 6) & 3;
        const int tn    = (i >> 8) & 7;
        const int n     = tn*16 + (lane2 & 15);
        const int kbase = ks*32 + (lane2 >> 4)*8;
        bf16x8 hv, lv;
        #pragma unroll
        for (int j = 0; j < 8; ++j){
            float w = Wg[(rowoff + kbase + j)*HID + n];
            short h = bf_t(w);
            hv[j] = h;
            lv[j] = bf_t(w - bf_u(h));
        }
        short* dst = slab + ((tn*4 + ks)*2)*FRAG + lane2*8;
        *(bf16x8*)(dst)        = hv;
        *(bf16x8*)(dst + FRAG) = lv;
    }
}

__device__ __forceinline__ void stage_hi_uv(const short* __restrict__ img,
                                            short* __restrict__ uv, int tid)
{
    const uint4* s = (const uint4*)img;
    uint4* d = (uint4*)uv;
    #pragma unroll
    for (int k = 0; k < 4; ++k){
        const int idx    = tid + k*1024;
        const int sl     = idx >> 11;
        const int within = idx & 2047;
        const int f      = within >> 6;
        const int w      = within & 63;
        d[idx] = s[(1 + sl)*4096 + f*128 + w];
    }
}

__device__ __forceinline__ void build_hi_uv(const float* __restrict__ Wc,
                                            short* __restrict__ uv, int tid)
{
    #pragma unroll
    for (int k = 0; k < 4; ++k){
        const int idx    = tid + k*1024;
        const int sl     = idx >> 11;
        const int within = idx & 2047;
        const int f      = within >> 6;
        const int lane2  = within & 63;
        const int tn = f >> 2, ks = f & 3;
        const int n     = tn*16 + (lane2 & 15);
        const int kbase = ks*32 + (lane2 >> 4)*8;
        const int rowoff = sl ? HID : 0;
        bf16x8 hv;
        #pragma unroll
        for (int j = 0; j < 8; ++j) hv[j] = bf_t(Wc[(rowoff + kbase + j)*HID + n]);
        *(bf16x8*)(uv + (size_t)idx*8) = hv;
    }
}

// 3-pass paired-tile GEMM (W2 only)
__device__ __forceinline__ void gemm16x2(const short* __restrict__ fbhi,
                                         const short* __restrict__ fblo,
                                         const short* __restrict__ slab,
                                         int tm, int tn0, int tn1, int lane,
                                         f32x4& c0, f32x4& c1)
{
    const int arow = tm*16 + (lane & 15);
    const int ko   = (lane >> 4) * 8;
    #pragma unroll 2
    for (int ks = 0; ks < 4; ++ks){
        bf16x8 ah = *(const bf16x8*)(fbhi + arow*KP + ks*32 + ko);
        bf16x8 al = *(const bf16x8*)(fblo + arow*KP + ks*32 + ko);
        const short* p0 = slab + ((tn0*4 + ks)*2)*FRAG + lane*8;
        const short* p1 = slab + ((tn1*4 + ks)*2)*FRAG + lane*8;
        bf16x8 bh0 = *(const bf16x8*)(p0);
        bf16x8 bl0 = *(const bf16x8*)(p0 + FRAG);
        bf16x8 bh1 = *(const bf16x8*)(p1);
        bf16x8 bl1 = *(const bf16x8*)(p1 + FRAG);
        c0 = __builtin_amdgcn_mfma_f32_16x16x32_bf16(ah, bh0, c0, 0,0,0);
        c0 = __builtin_amdgcn_mfma_f32_16x16x32_bf16(ah, bl0, c0, 0,0,0);
        c0 = __builtin_amdgcn_mfma_f32_16x16x32_bf16(al, bh0, c0, 0,0,0);
        c1 = __builtin_amdgcn_mfma_f32_16x16x32_bf16(ah, bh1, c1, 0,0,0);
        c1 = __builtin_amdgcn_mfma_f32_16x16x32_bf16(ah, bl1, c1, 0,0,0);
        c1 = __builtin_amdgcn_mfma_f32_16x16x32_bf16(al, bh1, c1, 0,0,0);
    }
}

extern "C" __global__ void __launch_bounds__(1024)
dgcnn_kernel(const float* __restrict__ x_pf,
             const float* __restrict__ W1, const float* __restrict__ b1,
             const float* __restrict__ W2, const float* __restrict__ b2,
             const float* __restrict__ Wc, const float* __restrict__ bc,
             const float* __restrict__ Wo1, const float* __restrict__ bo1,
             const float* __restrict__ Wo2, const float* __restrict__ bo2,
             const float* __restrict__ Wo3, const float* __restrict__ bo3,
             const float* __restrict__ Wo4, const float* __restrict__ bo4,
             const short* __restrict__ img, int use_img,
             float* __restrict__ out)
{
    __shared__ __align__(16) short fbhi[NN*KP];    // features hi / U hi
    __shared__ __align__(16) short fblo[NN*KP];
    __shared__ __align__(16) float dmt[NN*DP];     // distances
    __shared__ __align__(16) short Vbuf16[NN*VP];  // V as f16, col-pair interleaved; head scratch
    __shared__ __align__(16) short wslab[SLAB];    // W2 hi/lo -> [Uhi|Vhi] persistent
    __shared__ int   knn[NN*KK];                   // neighbor BYTE offsets into Vbuf16 rows
    __shared__ float sq[NN];

    const int tid  = threadIdx.x;
    const int g    = blockIdx.x;
    const int lane = tid & 63;
    const int wv   = tid >> 6;          // 0..15
    const int row1 = tid >> 4;          // 0..63
    const int c0i  = (tid & 15) * 8;
    const int c2   = (tid & 15) * 4;    // combine cols: {c2..c2+3, c2+64..c2+67}

    const int t0  = wv*2, t1 = wv*2 + 1;
    const int gtm = t0 >> 3;            // == wv>>2
    const int gtn0 = t0 & 7, gtn1 = t1 & 7;

    if (tid < NN) out[NG*8 + g*NN + tid] = (float)g;

    // ---- stage W2 slab (overlapped with W1 compute) ----
    if (use_img) stage_copy(img + 0*SLAB, wslab, tid); else stage_build(W2, 0, wslab, tid);

    // ---- W1: h1 = elu(x@W1+b1) -> hi/lo ----
    {
        float acc[8];
        {
            float4 bA = *(const float4*)(b1 + c0i);
            float4 bB = *(const float4*)(b1 + c0i + 4);
            acc[0]=bA.x; acc[1]=bA.y; acc[2]=bA.z; acc[3]=bA.w;
            acc[4]=bB.x; acc[5]=bB.y; acc[6]=bB.z; acc[7]=bB.w;
        }
        #pragma unroll
        for (int f = 0; f < 15; ++f){
            float xv = x_pf[g*NN*15 + row1*15 + f];
            float4 wA = *(const float4*)(W1 + f*HID + c0i);
            float4 wB = *(const float4*)(W1 + f*HID + c0i + 4);
            acc[0] += xv*wA.x; acc[1] += xv*wA.y; acc[2] += xv*wA.z; acc[3] += xv*wA.w;
            acc[4] += xv*wB.x; acc[5] += xv*wB.y; acc[6] += xv*wB.z; acc[7] += xv*wB.w;
        }
        short4 hA, lA, hB, lB;
        float v;
        v = elu1(acc[0]); hA.x = bf_t(v); lA.x = bf_t(v - bf_u(hA.x));
        v = elu1(acc[1]); hA.y = bf_t(v); lA.y = bf_t(v - bf_u(hA.y));
        v = elu1(acc[2]); hA.z = bf_t(v); lA.z = bf_t(v - bf_u(hA.z));
        v = elu1(acc[3]); hA.w = bf_t(v); lA.w = bf_t(v - bf_u(hA.w));
        v = elu1(acc[4]); hB.x = bf_t(v); lB.x = bf_t(v - bf_u(hB.x));
        v = elu1(acc[5]); hB.y = bf_t(v); lB.y = bf_t(v - bf_u(hB.y));
        v = elu1(acc[6]); hB.z = bf_t(v); lB.z = bf_t(v - bf_u(hB.z));
        v = elu1(acc[7]); hB.w = bf_t(v); lB.w = bf_t(v - bf_u(hB.w));
        *(short4*)(fbhi + row1*KP + c0i)     = hA;
        *(short4*)(fbhi + row1*KP + c0i + 4) = hB;
        *(short4*)(fblo + row1*KP + c0i)     = lA;
        *(short4*)(fblo + row1*KP + c0i + 4) = lB;
    }
    __syncthreads();

    // ---- W2 GEMM (3-pass): feat = elu(h1@W2 + b2); then stage persistent Uhi/Vhi ----
    {
        f32x4 cA = {0,0,0,0}, cB = {0,0,0,0};
        gemm16x2(fbhi, fblo, wslab, gtm, gtn0, gtn1, lane, cA, cB);
        __syncthreads();   // h1 reads + wslab reads complete
        #pragma unroll
        for (int half = 0; half < 2; ++half){
            const int tn  = half ? gtn1 : gtn0;
            const f32x4 c = half ? cB : cA;
            const int col = tn*16 + (lane & 15);
            const int rb  = gtm*16 + (lane >> 4)*4;
            const float bb = b2[col];
            #pragma unroll
            for (int e = 0; e < 4; ++e){
                float vv = elu1(c[e] + bb);
                short h = bf_t(vv);
                fbhi[(rb + e)*KP + col] = h;
                fblo[(rb + e)*KP + col] = bf_t(vv - bf_u(h));
            }
        }
        if (use_img) stage_hi_uv(img, wslab, tid); else build_hi_uv(Wc, wslab, tid);
    }
    __syncthreads();

    // ---- squared norms for layer 0 ----
    {
        bf16x8 hv = *(const bf16x8*)(fbhi + row1*KP + c0i);
        bf16x8 lv = *(const bf16x8*)(fblo + row1*KP + c0i);
        float s = 0.f;
        #pragma unroll
        for (int j = 0; j < 8; ++j){
            float vv = bf_u(hv[j]) + bf_u(lv[j]);
            s += vv*vv;
        }
        s += __shfl_xor(s, 1, 64);
        s += __shfl_xor(s, 2, 64);
        s += __shfl_xor(s, 4, 64);
        s += __shfl_xor(s, 8, 64);
        if ((tid & 15) == 0) sq[row1] = s;
    }
    __syncthreads();

    const short* Uhi = wslab;
    const short* Vhi = wslab + HSLAB;

    // ==== 3 EdgeConv layers (3 barriers each) ====
    for (int layer = 0; layer < 3; ++layer){
        // -- P1 (all-MFMA): dist (3-pass) + fused UV GEMM (1-pass A-hi), shared A-frags --
        f32x4 uA = {0,0,0,0}, uB = {0,0,0,0}, vA = {0,0,0,0}, vB = {0,0,0,0};
        {
            f32x4 dc = {0.f, 0.f, 0.f, 0.f};
            const int tm0 = wv >> 2, tn0d = wv & 3;
            const int arow = tm0*16 + (lane & 15);
            const int rB   = tn0d*16 + (lane & 15);
            const int ko   = (lane >> 4) * 8;
            #pragma unroll
            for (int ks = 0; ks < 4; ++ks){
                bf16x8 ah = *(const bf16x8*)(fbhi + arow*KP + ks*32 + ko);
                bf16x8 al = *(const bf16x8*)(fblo + arow*KP + ks*32 + ko);
                bf16x8 bh = *(const bf16x8*)(fbhi + rB*KP + ks*32 + ko);
                bf16x8 bl = *(const bf16x8*)(fblo + rB*KP + ks*32 + ko);
                dc = __builtin_amdgcn_mfma_f32_16x16x32_bf16(ah, bh, dc, 0,0,0);
                dc = __builtin_amdgcn_mfma_f32_16x16x32_bf16(ah, bl, dc, 0,0,0);
                dc = __builtin_amdgcn_mfma_f32_16x16x32_bf16(al, bh, dc, 0,0,0);
                const int f0 = (gtn0*4 + ks)*FRAG + lane*8;
                const int f1 = (gtn1*4 + ks)*FRAG + lane*8;
                bf16x8 bu0 = *(const bf16x8*)(Uhi + f0);
                bf16x8 bu1 = *(const bf16x8*)(Uhi + f1);
                bf16x8 bv0 = *(const bf16x8*)(Vhi + f0);
                bf16x8 bv1 = *(const bf16x8*)(Vhi + f1);
                uA = __builtin_amdgcn_mfma_f32_16x16x32_bf16(ah, bu0, uA, 0,0,0);
                uB = __builtin_amdgcn_mfma_f32_16x16x32_bf16(ah, bu1, uB, 0,0,0);
                vA = __builtin_amdgcn_mfma_f32_16x16x32_bf16(ah, bv0, vA, 0,0,0);
                vB = __builtin_amdgcn_mfma_f32_16x16x32_bf16(ah, bv1, vB, 0,0,0);
            }
            #pragma unroll
            for (int e = 0; e < 4; ++e){
                const int ra = tm0*16 + (lane >> 4)*4 + e, ca = tn0d*16 + (lane & 15);
                dmt[ra*DP + ca] = sq[ra] + sq[ca] - 2.f*dc[e];
            }
        }
        __syncthreads();

        // -- P2: write U(bf16 hi) -> fbhi, V(f16 pair-interleaved) -> Vbuf16;
        //        then kNN via wave-cooperative quickselect (byte offsets) --
        {
            #pragma unroll
            for (int half = 0; half < 2; ++half){
                const int tn  = half ? gtn1 : gtn0;
                const f32x4 cv = half ? vB : vA;
                const f32x4 cu = half ? uB : uA;
                const int col = tn*16 + (lane & 15);
                const int pc  = ((col & 63) << 1) + (col >> 6);   // interleaved position
                const int rb  = gtm*16 + (lane >> 4)*4;
                #pragma unroll
                for (int e = 0; e < 4; ++e){
                    Vbuf16[(rb + e)*VP + pc] = f2h(cv[e]);
                    fbhi[(rb + e)*KP + col] = bf_t(cu[e]);   // U stored hi-only
                }
            }
            #pragma unroll
            for (int p = 0; p < 4; ++p){
                const int r = wv*4 + p;
                const float dm = dmt[r*DP + lane];
                // quickselect: t = KK-th smallest across the wave's 64 values
                unsigned long long cand = ~0ull;
                float t = 0.f;
                for (int it = 0; it < 64; ++it){
                    const int pl = __builtin_ctzll(cand);
                    const float pv = __shfl(dm, pl, 64);
                    const unsigned long long lt = __ballot(dm < pv);
                    const int c = __popcll(lt);
                    if (c + 1 == KK){ t = pv; break; }
                    if (c + 1 > KK) cand &= lt;
                    else            cand &= ~(lt | (1ull << pl));
                    if (!cand){ t = pv; break; }   // duplicate fallback
                }
                // selection: all dm < t, plus lowest-index dm == t to fill KK
                unsigned long long sel = __ballot(dm < t);
                const int nlt = __popcll(sel);
                int need = KK - nlt;
                if (need > 0){
                    unsigned long long eq = __ballot(dm == t);
                    for (int i = 0; i < need; ++i){
                        unsigned long long b = eq & (~eq + 1ull);
                        if (!b) break;
                        sel |= b; eq ^= b;
                    }
                }
                if (sel & (1ull << lane)){
                    const int idx = __popcll(sel & ((1ull << lane) - 1ull));
                    if (idx < KK) knn[r*KK + idx] = lane * (VP*2);   // byte offset
                }
            }
        }
        __syncthreads();

        // -- P3: combine via packed-f16 max + fused next-layer sqnorm --
        {
            const int* kr = knn + row1*KK;
            int4 j0 = *(const int4*)(kr);
            int4 j1 = *(const int4*)(kr + 4);
            int4 j2 = *(const int4*)(kr + 8);
            int4 j3 = *(const int4*)(kr + 12);
            int4 j4 = *(const int4*)(kr + 16);
            int4 j5 = *(const int4*)(kr + 20);
            const char* Vb = (const char*)Vbuf16 + ((tid & 15) << 4);   // 16B per 4-col pair group
            unsigned mx0 = 0xFC00FC00u, mx1 = 0xFC00FC00u, mx2 = 0xFC00FC00u, mx3 = 0xFC00FC00u;
            #define GM(J) { \
                uint4 v = *(const uint4*)(Vb + (J)); \
                mx0 = pkmax(mx0, v.x); mx1 = pkmax(mx1, v.y); \
                mx2 = pkmax(mx2, v.z); mx3 = pkmax(mx3, v.w); }
            GM(j0.x) GM(j0.y) GM(j0.z) GM(j0.w)
            GM(j1.x) GM(j1.y) GM(j1.z) GM(j1.w)
            GM(j2.x) GM(j2.y) GM(j2.z) GM(j2.w)
            GM(j3.x) GM(j3.y) GM(j3.z) GM(j3.w)
            GM(j4.x) GM(j4.y) GM(j4.z) GM(j4.w)
            GM(j5.x) GM(j5.y) GM(j5.z) GM(j5.w)
            #undef GM
            float2 m0 = h22f2(mx0), m1 = h22f2(mx1), m2 = h22f2(mx2), m3 = h22f2(mx3);
            uint4 sv = *(const uint4*)(Vb + row1*(VP*2));
            float2 s0 = h22f2(sv.x), s1 = h22f2(sv.y), s2 = h22f2(sv.z), s3 = h22f2(sv.w);
            float4 bcA = *(const float4*)(bc + c2);
            float4 bcB = *(const float4*)(bc + c2 + 64);
            short4 uhA = *(const short4*)(fbhi + row1*KP + c2);
            short4 uhB = *(const short4*)(fbhi + row1*KP + c2 + 64);
            float o0 = elu1(bf_u(uhA.x) - s0.x + bcA.x + m0.x);
            float o1 = elu1(bf_u(uhA.y) - s1.x + bcA.y + m1.x);
            float o2 = elu1(bf_u(uhA.z) - s2.x + bcA.z + m2.x);
            float o3 = elu1(bf_u(uhA.w) - s3.x + bcA.w + m3.x);
            float o4 = elu1(bf_u(uhB.x) - s0.y + bcB.x + m0.y);
            float o5 = elu1(bf_u(uhB.y) - s1.y + bcB.y + m1.y);
            float o6 = elu1(bf_u(uhB.z) - s2.y + bcB.z + m2.y);
            float o7 = elu1(bf_u(uhB.w) - s3.y + bcB.w + m3.y);
            short4 nhA, nlA, nhB, nlB;
            nhA.x = bf_t(o0); nlA.x = bf_t(o0 - bf_u(nhA.x));
            nhA.y = bf_t(o1); nlA.y = bf_t(o1 - bf_u(nhA.y));
            nhA.z = bf_t(o2); nlA.z = bf_t(o2 - bf_u(nhA.z));
            nhA.w = bf_t(o3); nlA.w = bf_t(o3 - bf_u(nhA.w));
            nhB.x = bf_t(o4); nlB.x = bf_t(o4 - bf_u(nhB.x));
            nhB.y = bf_t(o5); nlB.y = bf_t(o5 - bf_u(nhB.y));
            nhB.z = bf_t(o6); nlB.z = bf_t(o6 - bf_u(nhB.z));
            nhB.w = bf_t(o7); nlB.w = bf_t(o7 - bf_u(nhB.w));
            *(short4*)(fbhi + row1*KP + c2)      = nhA;
            *(short4*)(fbhi + row1*KP + c2 + 64) = nhB;
            *(short4*)(fblo + row1*KP + c2)      = nlA;
            *(short4*)(fblo + row1*KP + c2 + 64) = nlB;
            float s = o0*o0 + o1*o1 + o2*o2 + o3*o3 + o4*o4 + o5*o5 + o6*o6 + o7*o7;
            s += __shfl_xor(s, 1, 64);
            s += __shfl_xor(s, 2, 64);
            s += __shfl_xor(s, 4, 64);
            s += __shfl_xor(s, 8, 64);
            if ((tid & 15) == 0) sq[row1] = s;
        }
        __syncthreads();
    }

    // ==== pooling + head (parallel multi-wave; scratch aliased into Vbuf16) ====
    float* pooled = (float*)Vbuf16;  // 128
    float* red    = pooled + 128;    // up to 1024
    float* hr1    = pooled + 1152;   // 64
    float* hr2    = pooled + 1216;   // 32
    float* hr3    = pooled + 1248;   // 32

    {
        const int pq = tid >> 7, ch = tid & 127;
        float s = 0.f;
        for (int n = pq*8; n < pq*8 + 8; ++n)
            s += bf_u(fbhi[n*KP + ch]) + bf_u(fblo[n*KP + ch]);
        red[pq*HID + ch] = s;
    }
    __syncthreads();
    if (tid < HID){
        float s = 0.f;
        #pragma unroll
        for (int p = 0; p < 8; ++p) s += red[p*HID + tid];
        pooled[tid] = s;
    }
    __syncthreads();
    if (tid < 256){
        const int o = tid & 63, part = tid >> 6;
        float s = 0.f;
        for (int f = part*32; f < part*32 + 32; ++f) s += pooled[f] * Wo1[f*64 + o];
        red[part*64 + o] = s;
    }
    __syncthreads();
    if (tid < 64) hr1[tid] = elu1(bo1[tid] + red[tid] + red[64+tid] + red[128+tid] + red[192+tid]);
    __syncthreads();
    if (tid < 128){
        const int o = tid & 31, part = tid >> 5;
        float s = 0.f;
        for (int f = part*16; f < part*16 + 16; ++f) s += hr1[f] * Wo2[f*32 + o];
        red[part*32 + o] = s;
    }
    __syncthreads();
    if (tid < 32) hr2[tid] = elu1(bo2[tid] + red[tid] + red[32+tid] + red[64+tid] + red[96+tid]);
    __syncthreads();
    if (tid < 32){
        float a = bo3[tid];
        for (int f = 0; f < 32; ++f) a += hr2[f] * Wo3[f*32 + tid];
        hr3[tid] = elu1(a);
    }
    __syncthreads();
    if (tid < 8){
        float a = bo4[tid];
        for (int f = 0; f < 32; ++f) a += hr3[f] * Wo4[f*8 + tid];
        out[g*8 + tid] = a;
    }
}

extern "C" void kernel_launch(void* const* d_in, const int* in_sizes, int n_in,
                              void* d_out, int out_size, void* d_ws, size_t ws_size,
                              hipStream_t stream) {
    short* img = (short*)d_ws;
    const int use_img = (ws_size >= (size_t)IMG_BYTES) ? 1 : 0;
    if (use_img) {
        const int total = 3*8*4*64;   // 6144 threads
        prep_kernel<<<(total + 255)/256, 256, 0, stream>>>(
            (const float*)d_in[4], (const float*)d_in[6], img);
    }
    dgcnn_kernel<<<NG, 1024, 0, stream>>>(
        (const float*)d_in[0],
        (const float*)d_in[2],  (const float*)d_in[3],
        (const float*)d_in[4],  (const float*)d_in[5],
        (const float*)d_in[6],  (const float*)d_in[7],
        (const float*)d_in[8],  (const float*)d_in[9],
        (const float*)d_in[10], (const float*)d_in[11],
        (const float*)d_in[12], (const float*)d_in[13],
        (const float*)d_in[14], (const float*)d_in[15],
        img, use_img,
        (float*)d_out);
}

// Round 17
// 47.712 us; speedup vs baseline: 1.1210x; 1.1210x over previous
//
#include <hip/hip_runtime.h>
#include <hip/hip_bf16.h>
#include <hip/hip_fp16.h>
#include <math.h>

#define NG  256
#define NN  64
#define KK  24
#define HID 128
#define KP  136   // bf16 LDS row stride (shorts): 272B
#define VP  136   // f16 V row stride (shorts): 272B
#define DP  68    // dmat row stride (floats)
#define FRAG 512                 // shorts per fragment (64 lanes x 8)
#define SLAB (8*4*2*FRAG)        // 32768 shorts per full hi/lo weight slab (64KB)
#define HSLAB (8*4*FRAG)         // 16384 shorts per hi-only compact slab (32KB)
#define IMG_BYTES (3*SLAB*2)     // 196608 B

typedef __attribute__((ext_vector_type(8)))  short bf16x8;
typedef __attribute__((ext_vector_type(4)))  float f32x4;

__device__ __forceinline__ float elu1(float x){ return x > 0.f ? x : (__expf(x)-1.f); }

// truncation-based bf16 split
__device__ __forceinline__ short bf_t(float x){ return (short)(__float_as_uint(x) >> 16); }
__device__ __forceinline__ float bf_u(short s){ return __uint_as_float(((unsigned)(unsigned short)s) << 16); }

__device__ __forceinline__ short f2h(float x){ __half h = __float2half(x); return *(short*)&h; }
__device__ __forceinline__ unsigned pkmax(unsigned a, unsigned b){
    unsigned r; asm("v_pk_max_f16 %0, %1, %2" : "=v"(r) : "v"(a), "v"(b)); return r;
}
__device__ __forceinline__ float2 h22f2(unsigned u){
    __half2 h = *(__half2*)&u; return __half22float2(h);
}

// ---- prep: weights -> 16x16-MFMA-fragment-ordered bf16 hi/lo images ----
extern "C" __global__ void prep_kernel(const float* __restrict__ W2,
                                       const float* __restrict__ Wc,
                                       short* __restrict__ img)
{
    int t = blockIdx.x * 256 + threadIdx.x;    // (s,tn,ks,lane)
    if (t >= 3*8*4*64) return;
    const int lane = t & 63;
    const int ks   = (t >> 6) & 3;
    const int tn   = (t >> 8) & 7;
    const int s    = t >> 11;
    const int n     = tn*16 + (lane & 15);
    const int kbase = ks*32 + (lane >> 4)*8;
    bf16x8 hv, lv;
    #pragma unroll
    for (int j = 0; j < 8; ++j){
        const int k = kbase + j;
        float w = (s == 0) ? W2[k*HID + n]
                : (s == 1) ? Wc[k*HID + n]
                           : Wc[(k + HID)*HID + n];
        short h = bf_t(w);
        hv[j] = h;
        lv[j] = bf_t(w - bf_u(h));
    }
    short* dst = img + s*SLAB + ((tn*4 + ks)*2)*FRAG + lane*8;
    *(bf16x8*)(dst)        = hv;
    *(bf16x8*)(dst + FRAG) = lv;
}

__device__ __forceinline__ void stage_copy(const short* __restrict__ src,
                                           short* __restrict__ slab, int tid)
{
    const uint4* s = (const uint4*)src;
    uint4* d = (uint4*)slab;
    #pragma unroll
    for (int i = 0; i < 4; ++i) d[tid + i*1024] = s[tid + i*1024];
}

__device__ __forceinline__ void stage_build(const float* __restrict__ Wg, int rowoff,
                                            short* __restrict__ slab, int tid)
{
    for (int i = tid; i < 8*4*64; i += 1024){
        const int lane2 = i & 63;
        const int ks    = (i >> 6) & 3;
        const int tn    = (i >> 8) & 7;
        const int n     = tn*16 + (lane2 & 15);
        const int kbase = ks*32 + (lane2 >> 4)*8;
        bf16x8 hv, lv;
        #pragma unroll
        for (int j = 0; j < 8; ++j){
            float w = Wg[(rowoff + kbase + j)*HID + n];
            short h = bf_t(w);
            hv[j] = h;
            lv[j] = bf_t(w - bf_u(h));
        }
        short* dst = slab + ((tn*4 + ks)*2)*FRAG + lane2*8;
        *(bf16x8*)(dst)        = hv;
        *(bf16x8*)(dst + FRAG) = lv;
    }
}

__device__ __forceinline__ void stage_hi_uv(const short* __restrict__ img,
                                            short* __restrict__ uv, int tid)
{
    const uint4* s = (const uint4*)img;
    uint4* d = (uint4*)uv;
    #pragma unroll
    for (int k = 0; k < 4; ++k){
        const int idx    = tid + k*1024;
        const int sl     = idx >> 11;
        const int within = idx & 2047;
        const int f      = within >> 6;
        const int w      = within & 63;
        d[idx] = s[(1 + sl)*4096 + f*128 + w];
    }
}

__device__ __forceinline__ void build_hi_uv(const float* __restrict__ Wc,
                                            short* __restrict__ uv, int tid)
{
    #pragma unroll
    for (int k = 0; k < 4; ++k){
        const int idx    = tid + k*1024;
        const int sl     = idx >> 11;
        const int within = idx & 2047;
        const int f      = within >> 6;
        const int lane2  = within & 63;
        const int tn = f >> 2, ks = f & 3;
        const int n     = tn*16 + (lane2 & 15);
        const int kbase = ks*32 + (lane2 >> 4)*8;
        const int rowoff = sl ? HID : 0;
        bf16x8 hv;
        #pragma unroll
        for (int j = 0; j < 8; ++j) hv[j] = bf_t(Wc[(rowoff + kbase + j)*HID + n]);
        *(bf16x8*)(uv + (size_t)idx*8) = hv;
    }
}

// 3-pass paired-tile GEMM (W2 only)
__device__ __forceinline__ void gemm16x2(const short* __restrict__ fbhi,
                                         const short* __restrict__ fblo,
                                         const short* __restrict__ slab,
                                         int tm, int tn0, int tn1, int lane,
                                         f32x4& c0, f32x4& c1)
{
    const int arow = tm*16 + (lane & 15);
    const int ko   = (lane >> 4) * 8;
    #pragma unroll 2
    for (int ks = 0; ks < 4; ++ks){
        bf16x8 ah = *(const bf16x8*)(fbhi + arow*KP + ks*32 + ko);
        bf16x8 al = *(const bf16x8*)(fblo + arow*KP + ks*32 + ko);
        const short* p0 = slab + ((tn0*4 + ks)*2)*FRAG + lane*8;
        const short* p1 = slab + ((tn1*4 + ks)*2)*FRAG + lane*8;
        bf16x8 bh0 = *(const bf16x8*)(p0);
        bf16x8 bl0 = *(const bf16x8*)(p0 + FRAG);
        bf16x8 bh1 = *(const bf16x8*)(p1);
        bf16x8 bl1 = *(const bf16x8*)(p1 + FRAG);
        c0 = __builtin_amdgcn_mfma_f32_16x16x32_bf16(ah, bh0, c0, 0,0,0);
        c0 = __builtin_amdgcn_mfma_f32_16x16x32_bf16(ah, bl0, c0, 0,0,0);
        c0 = __builtin_amdgcn_mfma_f32_16x16x32_bf16(al, bh0, c0, 0,0,0);
        c1 = __builtin_amdgcn_mfma_f32_16x16x32_bf16(ah, bh1, c1, 0,0,0);
        c1 = __builtin_amdgcn_mfma_f32_16x16x32_bf16(ah, bl1, c1, 0,0,0);
        c1 = __builtin_amdgcn_mfma_f32_16x16x32_bf16(al, bh1, c1, 0,0,0);
    }
}

extern "C" __global__ void __launch_bounds__(1024)
dgcnn_kernel(const float* __restrict__ x_pf,
             const float* __restrict__ W1, const float* __restrict__ b1,
             const float* __restrict__ W2, const float* __restrict__ b2,
             const float* __restrict__ Wc, const float* __restrict__ bc,
             const float* __restrict__ Wo1, const float* __restrict__ bo1,
             const float* __restrict__ Wo2, const float* __restrict__ bo2,
             const float* __restrict__ Wo3, const float* __restrict__ bo3,
             const float* __restrict__ Wo4, const float* __restrict__ bo4,
             const short* __restrict__ img, int use_img,
             float* __restrict__ out)
{
    __shared__ __align__(16) short fbhi[NN*KP];    // features hi / U hi
    __shared__ __align__(16) short fblo[NN*KP];
    __shared__ __align__(16) float dmt[NN*DP];     // distances
    __shared__ __align__(16) short Vbuf16[NN*VP];  // V as f16, col-pair interleaved; head scratch
    __shared__ __align__(16) short wslab[SLAB];    // W2 hi/lo -> [Uhi|Vhi] persistent
    __shared__ int   knn[NN*KK];                   // neighbor BYTE offsets into Vbuf16 rows
    __shared__ float sq[NN];

    const int tid  = threadIdx.x;
    const int g    = blockIdx.x;
    const int lane = tid & 63;
    const int wv   = tid >> 6;          // 0..15
    const int row1 = tid >> 4;          // 0..63
    const int c0i  = (tid & 15) * 8;
    const int c2   = (tid & 15) * 4;    // combine cols: {c2..c2+3, c2+64..c2+67}

    const int t0  = wv*2, t1 = wv*2 + 1;
    const int gtm = t0 >> 3;            // == wv>>2
    const int gtn0 = t0 & 7, gtn1 = t1 & 7;

    if (tid < NN) out[NG*8 + g*NN + tid] = (float)g;

    // ---- stage W2 slab (overlapped with W1 compute) ----
    if (use_img) stage_copy(img + 0*SLAB, wslab, tid); else stage_build(W2, 0, wslab, tid);

    // ---- W1: h1 = elu(x@W1+b1) -> hi/lo ----
    {
        float acc[8];
        {
            float4 bA = *(const float4*)(b1 + c0i);
            float4 bB = *(const float4*)(b1 + c0i + 4);
            acc[0]=bA.x; acc[1]=bA.y; acc[2]=bA.z; acc[3]=bA.w;
            acc[4]=bB.x; acc[5]=bB.y; acc[6]=bB.z; acc[7]=bB.w;
        }
        #pragma unroll
        for (int f = 0; f < 15; ++f){
            float xv = x_pf[g*NN*15 + row1*15 + f];
            float4 wA = *(const float4*)(W1 + f*HID + c0i);
            float4 wB = *(const float4*)(W1 + f*HID + c0i + 4);
            acc[0] += xv*wA.x; acc[1] += xv*wA.y; acc[2] += xv*wA.z; acc[3] += xv*wA.w;
            acc[4] += xv*wB.x; acc[5] += xv*wB.y; acc[6] += xv*wB.z; acc[7] += xv*wB.w;
        }
        short4 hA, lA, hB, lB;
        float v;
        v = elu1(acc[0]); hA.x = bf_t(v); lA.x = bf_t(v - bf_u(hA.x));
        v = elu1(acc[1]); hA.y = bf_t(v); lA.y = bf_t(v - bf_u(hA.y));
        v = elu1(acc[2]); hA.z = bf_t(v); lA.z = bf_t(v - bf_u(hA.z));
        v = elu1(acc[3]); hA.w = bf_t(v); lA.w = bf_t(v - bf_u(hA.w));
        v = elu1(acc[4]); hB.x = bf_t(v); lB.x = bf_t(v - bf_u(hB.x));
        v = elu1(acc[5]); hB.y = bf_t(v); lB.y = bf_t(v - bf_u(hB.y));
        v = elu1(acc[6]); hB.z = bf_t(v); lB.z = bf_t(v - bf_u(hB.z));
        v = elu1(acc[7]); hB.w = bf_t(v); lB.w = bf_t(v - bf_u(hB.w));
        *(short4*)(fbhi + row1*KP + c0i)     = hA;
        *(short4*)(fbhi + row1*KP + c0i + 4) = hB;
        *(short4*)(fblo + row1*KP + c0i)     = lA;
        *(short4*)(fblo + row1*KP + c0i + 4) = lB;
    }
    __syncthreads();

    // ---- W2 GEMM (3-pass): feat = elu(h1@W2 + b2); then stage persistent Uhi/Vhi ----
    {
        f32x4 cA = {0,0,0,0}, cB = {0,0,0,0};
        gemm16x2(fbhi, fblo, wslab, gtm, gtn0, gtn1, lane, cA, cB);
        __syncthreads();   // h1 reads + wslab reads complete
        #pragma unroll
        for (int half = 0; half < 2; ++half){
            const int tn  = half ? gtn1 : gtn0;
            const f32x4 c = half ? cB : cA;
            const int col = tn*16 + (lane & 15);
            const int rb  = gtm*16 + (lane >> 4)*4;
            const float bb = b2[col];
            #pragma unroll
            for (int e = 0; e < 4; ++e){
                float vv = elu1(c[e] + bb);
                short h = bf_t(vv);
                fbhi[(rb + e)*KP + col] = h;
                fblo[(rb + e)*KP + col] = bf_t(vv - bf_u(h));
            }
        }
        if (use_img) stage_hi_uv(img, wslab, tid); else build_hi_uv(Wc, wslab, tid);
    }
    __syncthreads();

    // ---- squared norms for layer 0 ----
    {
        bf16x8 hv = *(const bf16x8*)(fbhi + row1*KP + c0i);
        bf16x8 lv = *(const bf16x8*)(fblo + row1*KP + c0i);
        float s = 0.f;
        #pragma unroll
        for (int j = 0; j < 8; ++j){
            float vv = bf_u(hv[j]) + bf_u(lv[j]);
            s += vv*vv;
        }
        s += __shfl_xor(s, 1, 64);
        s += __shfl_xor(s, 2, 64);
        s += __shfl_xor(s, 4, 64);
        s += __shfl_xor(s, 8, 64);
        if ((tid & 15) == 0) sq[row1] = s;
    }
    __syncthreads();

    const short* Uhi = wslab;
    const short* Vhi = wslab + HSLAB;

    // ==== 3 EdgeConv layers (3 barriers each) ====
    for (int layer = 0; layer < 3; ++layer){
        // -- P1 (all-MFMA): dist (3-pass) + fused UV GEMM (1-pass A-hi), shared A-frags --
        f32x4 uA = {0,0,0,0}, uB = {0,0,0,0}, vA = {0,0,0,0}, vB = {0,0,0,0};
        {
            f32x4 dc = {0.f, 0.f, 0.f, 0.f};
            const int tm0 = wv >> 2, tn0d = wv & 3;
            const int arow = tm0*16 + (lane & 15);
            const int rB   = tn0d*16 + (lane & 15);
            const int ko   = (lane >> 4) * 8;
            #pragma unroll
            for (int ks = 0; ks < 4; ++ks){
                bf16x8 ah = *(const bf16x8*)(fbhi + arow*KP + ks*32 + ko);
                bf16x8 al = *(const bf16x8*)(fblo + arow*KP + ks*32 + ko);
                bf16x8 bh = *(const bf16x8*)(fbhi + rB*KP + ks*32 + ko);
                bf16x8 bl = *(const bf16x8*)(fblo + rB*KP + ks*32 + ko);
                dc = __builtin_amdgcn_mfma_f32_16x16x32_bf16(ah, bh, dc, 0,0,0);
                dc = __builtin_amdgcn_mfma_f32_16x16x32_bf16(ah, bl, dc, 0,0,0);
                dc = __builtin_amdgcn_mfma_f32_16x16x32_bf16(al, bh, dc, 0,0,0);
                const int f0 = (gtn0*4 + ks)*FRAG + lane*8;
                const int f1 = (gtn1*4 + ks)*FRAG + lane*8;
                bf16x8 bu0 = *(const bf16x8*)(Uhi + f0);
                bf16x8 bu1 = *(const bf16x8*)(Uhi + f1);
                bf16x8 bv0 = *(const bf16x8*)(Vhi + f0);
                bf16x8 bv1 = *(const bf16x8*)(Vhi + f1);
                uA = __builtin_amdgcn_mfma_f32_16x16x32_bf16(ah, bu0, uA, 0,0,0);
                uB = __builtin_amdgcn_mfma_f32_16x16x32_bf16(ah, bu1, uB, 0,0,0);
                vA = __builtin_amdgcn_mfma_f32_16x16x32_bf16(ah, bv0, vA, 0,0,0);
                vB = __builtin_amdgcn_mfma_f32_16x16x32_bf16(ah, bv1, vB, 0,0,0);
            }
            #pragma unroll
            for (int e = 0; e < 4; ++e){
                const int ra = tm0*16 + (lane >> 4)*4 + e, ca = tn0d*16 + (lane & 15);
                dmt[ra*DP + ca] = sq[ra] + sq[ca] - 2.f*dc[e];
            }
        }
        __syncthreads();

        // -- P2: write U(bf16 hi) -> fbhi, V(f16 pair-interleaved) -> Vbuf16;
        //        then kNN via streamed rank counting (byte offsets) --
        {
            #pragma unroll
            for (int half = 0; half < 2; ++half){
                const int tn  = half ? gtn1 : gtn0;
                const f32x4 cv = half ? vB : vA;
                const f32x4 cu = half ? uB : uA;
                const int col = tn*16 + (lane & 15);
                const int pc  = ((col & 63) << 1) + (col >> 6);   // interleaved position
                const int rb  = gtm*16 + (lane >> 4)*4;
                #pragma unroll
                for (int e = 0; e < 4; ++e){
                    Vbuf16[(rb + e)*VP + pc] = f2h(cv[e]);
                    fbhi[(rb + e)*KP + col] = bf_t(cu[e]);   // U stored hi-only
                }
            }
            #pragma unroll
            for (int p = 0; p < 4; ++p){
                const int r = wv*4 + p;
                const float dm = dmt[r*DP + lane];
                int rank = 0;
                #pragma unroll 4
                for (int q = 0; q < 16; ++q){
                    float4 v = *(const float4*)(dmt + r*DP + q*4);
                    rank += (v.x < dm) + (v.y < dm) + (v.z < dm) + (v.w < dm);
                }
                const unsigned long long mask = __ballot(rank < KK);
                if (rank < KK){
                    const int c = __popcll(mask & ((1ULL << lane) - 1ULL));
                    if (c < KK) knn[r*KK + c] = lane * (VP*2);   // byte offset
                }
            }
        }
        __syncthreads();

        // -- P3: combine via packed-f16 max + fused next-layer sqnorm --
        {
            const int* kr = knn + row1*KK;
            int4 j0 = *(const int4*)(kr);
            int4 j1 = *(const int4*)(kr + 4);
            int4 j2 = *(const int4*)(kr + 8);
            int4 j3 = *(const int4*)(kr + 12);
            int4 j4 = *(const int4*)(kr + 16);
            int4 j5 = *(const int4*)(kr + 20);
            const char* Vb = (const char*)Vbuf16 + ((tid & 15) << 4);   // 16B per 4-col pair group
            unsigned mx0 = 0xFC00FC00u, mx1 = 0xFC00FC00u, mx2 = 0xFC00FC00u, mx3 = 0xFC00FC00u;
            #define GM(J) { \
                uint4 v = *(const uint4*)(Vb + (J)); \
                mx0 = pkmax(mx0, v.x); mx1 = pkmax(mx1, v.y); \
                mx2 = pkmax(mx2, v.z); mx3 = pkmax(mx3, v.w); }
            GM(j0.x) GM(j0.y) GM(j0.z) GM(j0.w)
            GM(j1.x) GM(j1.y) GM(j1.z) GM(j1.w)
            GM(j2.x) GM(j2.y) GM(j2.z) GM(j2.w)
            GM(j3.x) GM(j3.y) GM(j3.z) GM(j3.w)
            GM(j4.x) GM(j4.y) GM(j4.z) GM(j4.w)
            GM(j5.x) GM(j5.y) GM(j5.z) GM(j5.w)
            #undef GM
            float2 m0 = h22f2(mx0), m1 = h22f2(mx1), m2 = h22f2(mx2), m3 = h22f2(mx3);
            uint4 sv = *(const uint4*)(Vb + row1*(VP*2));
            float2 s0 = h22f2(sv.x), s1 = h22f2(sv.y), s2 = h22f2(sv.z), s3 = h22f2(sv.w);
            float4 bcA = *(const float4*)(bc + c2);
            float4 bcB = *(const float4*)(bc + c2 + 64);
            short4 uhA = *(const short4*)(fbhi + row1*KP + c2);
            short4 uhB = *(const short4*)(fbhi + row1*KP + c2 + 64);
            float o0 = elu1(bf_u(uhA.x) - s0.x + bcA.x + m0.x);
            float o1 = elu1(bf_u(uhA.y) - s1.x + bcA.y + m1.x);
            float o2 = elu1(bf_u(uhA.z) - s2.x + bcA.z + m2.x);
            float o3 = elu1(bf_u(uhA.w) - s3.x + bcA.w + m3.x);
            float o4 = elu1(bf_u(uhB.x) - s0.y + bcB.x + m0.y);
            float o5 = elu1(bf_u(uhB.y) - s1.y + bcB.y + m1.y);
            float o6 = elu1(bf_u(uhB.z) - s2.y + bcB.z + m2.y);
            float o7 = elu1(bf_u(uhB.w) - s3.y + bcB.w + m3.y);
            short4 nhA, nlA, nhB, nlB;
            nhA.x = bf_t(o0); nlA.x = bf_t(o0 - bf_u(nhA.x));
            nhA.y = bf_t(o1); nlA.y = bf_t(o1 - bf_u(nhA.y));
            nhA.z = bf_t(o2); nlA.z = bf_t(o2 - bf_u(nhA.z));
            nhA.w = bf_t(o3); nlA.w = bf_t(o3 - bf_u(nhA.w));
            nhB.x = bf_t(o4); nlB.x = bf_t(o4 - bf_u(nhB.x));
            nhB.y = bf_t(o5); nlB.y = bf_t(o5 - bf_u(nhB.y));
            nhB.z = bf_t(o6); nlB.z = bf_t(o6 - bf_u(nhB.z));
            nhB.w = bf_t(o7); nlB.w = bf_t(o7 - bf_u(nhB.w));
            *(short4*)(fbhi + row1*KP + c2)      = nhA;
            *(short4*)(fbhi + row1*KP + c2 + 64) = nhB;
            *(short4*)(fblo + row1*KP + c2)      = nlA;
            *(short4*)(fblo + row1*KP + c2 + 64) = nlB;
            float s = o0*o0 + o1*o1 + o2*o2 + o3*o3 + o4*o4 + o5*o5 + o6*o6 + o7*o7;
            s += __shfl_xor(s, 1, 64);
            s += __shfl_xor(s, 2, 64);
            s += __shfl_xor(s, 4, 64);
            s += __shfl_xor(s, 8, 64);
            if ((tid & 15) == 0) sq[row1] = s;
        }
        __syncthreads();
    }

    // ==== pooling + head (parallel multi-wave; scratch aliased into Vbuf16) ====
    float* pooled = (float*)Vbuf16;  // 128
    float* red    = pooled + 128;    // up to 1024
    float* hr1    = pooled + 1152;   // 64
    float* hr2    = pooled + 1216;   // 32
    float* hr3    = pooled + 1248;   // 32

    {
        const int pq = tid >> 7, ch = tid & 127;
        float s = 0.f;
        for (int n = pq*8; n < pq*8 + 8; ++n)
            s += bf_u(fbhi[n*KP + ch]) + bf_u(fblo[n*KP + ch]);
        red[pq*HID + ch] = s;
    }
    __syncthreads();
    if (tid < HID){
        float s = 0.f;
        #pragma unroll
        for (int p = 0; p < 8; ++p) s += red[p*HID + tid];
        pooled[tid] = s;
    }
    __syncthreads();
    if (tid < 256){
        const int o = tid & 63, part = tid >> 6;
        float s = 0.f;
        for (int f = part*32; f < part*32 + 32; ++f) s += pooled[f] * Wo1[f*64 + o];
        red[part*64 + o] = s;
    }
    __syncthreads();
    if (tid < 64) hr1[tid] = elu1(bo1[tid] + red[tid] + red[64+tid] + red[128+tid] + red[192+tid]);
    __syncthreads();
    if (tid < 128){
        const int o = tid & 31, part = tid >> 5;
        float s = 0.f;
        for (int f = part*16; f < part*16 + 16; ++f) s += hr1[f] * Wo2[f*32 + o];
        red[part*32 + o] = s;
    }
    __syncthreads();
    if (tid < 32) hr2[tid] = elu1(bo2[tid] + red[tid] + red[32+tid] + red[64+tid] + red[96+tid]);
    __syncthreads();
    if (tid < 32){
        float a = bo3[tid];
        for (int f = 0; f < 32; ++f) a += hr2[f] * Wo3[f*32 + tid];
        hr3[tid] = elu1(a);
    }
    __syncthreads();
    if (tid < 8){
        float a = bo4[tid];
        for (int f = 0; f < 32; ++f) a += hr3[f] * Wo4[f*8 + tid];
        out[g*8 + tid] = a;
    }
}

extern "C" void kernel_launch(void* const* d_in, const int* in_sizes, int n_in,
                              void* d_out, int out_size, void* d_ws, size_t ws_size,
                              hipStream_t stream) {
    short* img = (short*)d_ws;
    const int use_img = (ws_size >= (size_t)IMG_BYTES) ? 1 : 0;
    if (use_img) {
        const int total = 3*8*4*64;   // 6144 threads
        prep_kernel<<<(total + 255)/256, 256, 0, stream>>>(
            (const float*)d_in[4], (const float*)d_in[6], img);
    }
    dgcnn_kernel<<<NG, 1024, 0, stream>>>(
        (const float*)d_in[0],
        (const float*)d_in[2],  (const float*)d_in[3],
        (const float*)d_in[4],  (const float*)d_in[5],
        (const float*)d_in[6],  (const float*)d_in[7],
        (const float*)d_in[8],  (const float*)d_in[9],
        (const float*)d_in[10], (const float*)d_in[11],
        (const float*)d_in[12], (const float*)d_in[13],
        (const float*)d_in[14], (const float*)d_in[15],
        img, use_img,
        (float*)d_out);
}

// Round 18
// 47.615 us; speedup vs baseline: 1.1233x; 1.0020x over previous
//
#include <hip/hip_runtime.h>
#include <hip/hip_bf16.h>
#include <hip/hip_fp16.h>
#include <math.h>

#define NG  256
#define NN  64
#define KK  24
#define HID 128
#define KP  136   // bf16 LDS row stride (shorts): 272B
#define VP  136   // f16 V row stride (shorts): 272B
#define DP  68    // dmat row stride (floats)
#define FRAG 512                 // shorts per fragment (64 lanes x 8)
#define SLAB (8*4*2*FRAG)        // 32768 shorts per full hi/lo weight slab (64KB)
#define HSLAB (8*4*FRAG)         // 16384 shorts per hi-only compact slab (32KB)
#define IMG_BYTES (3*SLAB*2)     // 196608 B

typedef __attribute__((ext_vector_type(8)))  short bf16x8;
typedef __attribute__((ext_vector_type(4)))  float f32x4;

__device__ __forceinline__ float elu1(float x){ return x > 0.f ? x : (__expf(x)-1.f); }

// truncation-based bf16 split
__device__ __forceinline__ short bf_t(float x){ return (short)(__float_as_uint(x) >> 16); }
__device__ __forceinline__ float bf_u(short s){ return __uint_as_float(((unsigned)(unsigned short)s) << 16); }

__device__ __forceinline__ short f2h(float x){ __half h = __float2half(x); return *(short*)&h; }
__device__ __forceinline__ unsigned pkmax(unsigned a, unsigned b){
    unsigned r; asm("v_pk_max_f16 %0, %1, %2" : "=v"(r) : "v"(a), "v"(b)); return r;
}
__device__ __forceinline__ float2 h22f2(unsigned u){
    __half2 h = *(__half2*)&u; return __half22float2(h);
}

// ---- prep: weights -> 16x16-MFMA-fragment-ordered bf16 hi/lo images ----
extern "C" __global__ void prep_kernel(const float* __restrict__ W2,
                                       const float* __restrict__ Wc,
                                       short* __restrict__ img)
{
    int t = blockIdx.x * 256 + threadIdx.x;    // (s,tn,ks,lane)
    if (t >= 3*8*4*64) return;
    const int lane = t & 63;
    const int ks   = (t >> 6) & 3;
    const int tn   = (t >> 8) & 7;
    const int s    = t >> 11;
    const int n     = tn*16 + (lane & 15);
    const int kbase = ks*32 + (lane >> 4)*8;
    bf16x8 hv, lv;
    #pragma unroll
    for (int j = 0; j < 8; ++j){
        const int k = kbase + j;
        float w = (s == 0) ? W2[k*HID + n]
                : (s == 1) ? Wc[k*HID + n]
                           : Wc[(k + HID)*HID + n];
        short h = bf_t(w);
        hv[j] = h;
        lv[j] = bf_t(w - bf_u(h));
    }
    short* dst = img + s*SLAB + ((tn*4 + ks)*2)*FRAG + lane*8;
    *(bf16x8*)(dst)        = hv;
    *(bf16x8*)(dst + FRAG) = lv;
}

__device__ __forceinline__ void stage_copy(const short* __restrict__ src,
                                           short* __restrict__ slab, int tid)
{
    const uint4* s = (const uint4*)src;
    uint4* d = (uint4*)slab;
    #pragma unroll
    for (int i = 0; i < 4; ++i) d[tid + i*1024] = s[tid + i*1024];
}

__device__ __forceinline__ void stage_build(const float* __restrict__ Wg, int rowoff,
                                            short* __restrict__ slab, int tid)
{
    for (int i = tid; i < 8*4*64; i += 1024){
        const int lane2 = i & 63;
        const int ks    = (i >> 6) & 3;
        const int tn    = (i >> 8) & 7;
        const int n     = tn*16 + (lane2 & 15);
        const int kbase = ks*32 + (lane2 >> 4)*8;
        bf16x8 hv, lv;
        #pragma unroll
        for (int j = 0; j < 8; ++j){
            float w = Wg[(rowoff + kbase + j)*HID + n];
            short h = bf_t(w);
            hv[j] = h;
            lv[j] = bf_t(w - bf_u(h));
        }
        short* dst = slab + ((tn*4 + ks)*2)*FRAG + lane2*8;
        *(bf16x8*)(dst)        = hv;
        *(bf16x8*)(dst + FRAG) = lv;
    }
}

__device__ __forceinline__ void stage_hi_uv(const short* __restrict__ img,
                                            short* __restrict__ uv, int tid)
{
    const uint4* s = (const uint4*)img;
    uint4* d = (uint4*)uv;
    #pragma unroll
    for (int k = 0; k < 4; ++k){
        const int idx    = tid + k*1024;
        const int sl     = idx >> 11;
        const int within = idx & 2047;
        const int f      = within >> 6;
        const int w      = within & 63;
        d[idx] = s[(1 + sl)*4096 + f*128 + w];
    }
}

__device__ __forceinline__ void build_hi_uv(const float* __restrict__ Wc,
                                            short* __restrict__ uv, int tid)
{
    #pragma unroll
    for (int k = 0; k < 4; ++k){
        const int idx    = tid + k*1024;
        const int sl     = idx >> 11;
        const int within = idx & 2047;
        const int f      = within >> 6;
        const int lane2  = within & 63;
        const int tn = f >> 2, ks = f & 3;
        const int n     = tn*16 + (lane2 & 15);
        const int kbase = ks*32 + (lane2 >> 4)*8;
        const int rowoff = sl ? HID : 0;
        bf16x8 hv;
        #pragma unroll
        for (int j = 0; j < 8; ++j) hv[j] = bf_t(Wc[(rowoff + kbase + j)*HID + n]);
        *(bf16x8*)(uv + (size_t)idx*8) = hv;
    }
}

// 3-pass paired-tile GEMM (W2 only)
__device__ __forceinline__ void gemm16x2(const short* __restrict__ fbhi,
                                         const short* __restrict__ fblo,
                                         const short* __restrict__ slab,
                                         int tm, int tn0, int tn1, int lane,
                                         f32x4& c0, f32x4& c1)
{
    const int arow = tm*16 + (lane & 15);
    const int ko   = (lane >> 4) * 8;
    #pragma unroll 2
    for (int ks = 0; ks < 4; ++ks){
        bf16x8 ah = *(const bf16x8*)(fbhi + arow*KP + ks*32 + ko);
        bf16x8 al = *(const bf16x8*)(fblo + arow*KP + ks*32 + ko);
        const short* p0 = slab + ((tn0*4 + ks)*2)*FRAG + lane*8;
        const short* p1 = slab + ((tn1*4 + ks)*2)*FRAG + lane*8;
        bf16x8 bh0 = *(const bf16x8*)(p0);
        bf16x8 bl0 = *(const bf16x8*)(p0 + FRAG);
        bf16x8 bh1 = *(const bf16x8*)(p1);
        bf16x8 bl1 = *(const bf16x8*)(p1 + FRAG);
        c0 = __builtin_amdgcn_mfma_f32_16x16x32_bf16(ah, bh0, c0, 0,0,0);
        c0 = __builtin_amdgcn_mfma_f32_16x16x32_bf16(ah, bl0, c0, 0,0,0);
        c0 = __builtin_amdgcn_mfma_f32_16x16x32_bf16(al, bh0, c0, 0,0,0);
        c1 = __builtin_amdgcn_mfma_f32_16x16x32_bf16(ah, bh1, c1, 0,0,0);
        c1 = __builtin_amdgcn_mfma_f32_16x16x32_bf16(ah, bl1, c1, 0,0,0);
        c1 = __builtin_amdgcn_mfma_f32_16x16x32_bf16(al, bh1, c1, 0,0,0);
    }
}

extern "C" __global__ void __launch_bounds__(1024)
dgcnn_kernel(const float* __restrict__ x_pf,
             const float* __restrict__ W1, const float* __restrict__ b1,
             const float* __restrict__ W2, const float* __restrict__ b2,
             const float* __restrict__ Wc, const float* __restrict__ bc,
             const float* __restrict__ Wo1, const float* __restrict__ bo1,
             const float* __restrict__ Wo2, const float* __restrict__ bo2,
             const float* __restrict__ Wo3, const float* __restrict__ bo3,
             const float* __restrict__ Wo4, const float* __restrict__ bo4,
             const short* __restrict__ img, int use_img,
             float* __restrict__ out)
{
    __shared__ __align__(16) short fbhi[NN*KP];    // features hi / U hi
    __shared__ __align__(16) short fblo[NN*KP];
    __shared__ __align__(16) float dmt[NN*DP];     // distances; layer-2: pool partials + head scratch
    __shared__ __align__(16) short Vbuf16[NN*VP];  // V as f16, col-pair interleaved
    __shared__ __align__(16) short wslab[SLAB];    // W2 hi/lo -> [Uhi|Vhi] persistent
    __shared__ int   knn[NN*KK];                   // neighbor BYTE offsets into Vbuf16 rows
    __shared__ float sq[NN];

    const int tid  = threadIdx.x;
    const int g    = blockIdx.x;
    const int lane = tid & 63;
    const int wv   = tid >> 6;          // 0..15
    const int row1 = tid >> 4;          // 0..63
    const int c0i  = (tid & 15) * 8;
    const int c2   = (tid & 15) * 4;    // combine cols: {c2..c2+3, c2+64..c2+67}

    const int t0  = wv*2, t1 = wv*2 + 1;
    const int gtm = t0 >> 3;            // == wv>>2
    const int gtn0 = t0 & 7, gtn1 = t1 & 7;

    if (tid < NN) out[NG*8 + g*NN + tid] = (float)g;

    // ---- stage W2 slab (overlapped with W1 compute) ----
    if (use_img) stage_copy(img + 0*SLAB, wslab, tid); else stage_build(W2, 0, wslab, tid);

    // ---- W1: h1 = elu(x@W1+b1) -> hi/lo ----
    {
        float acc[8];
        {
            float4 bA = *(const float4*)(b1 + c0i);
            float4 bB = *(const float4*)(b1 + c0i + 4);
            acc[0]=bA.x; acc[1]=bA.y; acc[2]=bA.z; acc[3]=bA.w;
            acc[4]=bB.x; acc[5]=bB.y; acc[6]=bB.z; acc[7]=bB.w;
        }
        #pragma unroll
        for (int f = 0; f < 15; ++f){
            float xv = x_pf[g*NN*15 + row1*15 + f];
            float4 wA = *(const float4*)(W1 + f*HID + c0i);
            float4 wB = *(const float4*)(W1 + f*HID + c0i + 4);
            acc[0] += xv*wA.x; acc[1] += xv*wA.y; acc[2] += xv*wA.z; acc[3] += xv*wA.w;
            acc[4] += xv*wB.x; acc[5] += xv*wB.y; acc[6] += xv*wB.z; acc[7] += xv*wB.w;
        }
        short4 hA, lA, hB, lB;
        float v;
        v = elu1(acc[0]); hA.x = bf_t(v); lA.x = bf_t(v - bf_u(hA.x));
        v = elu1(acc[1]); hA.y = bf_t(v); lA.y = bf_t(v - bf_u(hA.y));
        v = elu1(acc[2]); hA.z = bf_t(v); lA.z = bf_t(v - bf_u(hA.z));
        v = elu1(acc[3]); hA.w = bf_t(v); lA.w = bf_t(v - bf_u(hA.w));
        v = elu1(acc[4]); hB.x = bf_t(v); lB.x = bf_t(v - bf_u(hB.x));
        v = elu1(acc[5]); hB.y = bf_t(v); lB.y = bf_t(v - bf_u(hB.y));
        v = elu1(acc[6]); hB.z = bf_t(v); lB.z = bf_t(v - bf_u(hB.z));
        v = elu1(acc[7]); hB.w = bf_t(v); lB.w = bf_t(v - bf_u(hB.w));
        *(short4*)(fbhi + row1*KP + c0i)     = hA;
        *(short4*)(fbhi + row1*KP + c0i + 4) = hB;
        *(short4*)(fblo + row1*KP + c0i)     = lA;
        *(short4*)(fblo + row1*KP + c0i + 4) = lB;
    }
    __syncthreads();

    // ---- W2 GEMM (3-pass): feat = elu(h1@W2 + b2); then stage persistent Uhi/Vhi ----
    {
        f32x4 cA = {0,0,0,0}, cB = {0,0,0,0};
        gemm16x2(fbhi, fblo, wslab, gtm, gtn0, gtn1, lane, cA, cB);
        __syncthreads();   // h1 reads + wslab reads complete
        #pragma unroll
        for (int half = 0; half < 2; ++half){
            const int tn  = half ? gtn1 : gtn0;
            const f32x4 c = half ? cB : cA;
            const int col = tn*16 + (lane & 15);
            const int rb  = gtm*16 + (lane >> 4)*4;
            const float bb = b2[col];
            #pragma unroll
            for (int e = 0; e < 4; ++e){
                float vv = elu1(c[e] + bb);
                short h = bf_t(vv);
                fbhi[(rb + e)*KP + col] = h;
                fblo[(rb + e)*KP + col] = bf_t(vv - bf_u(h));
            }
        }
        if (use_img) stage_hi_uv(img, wslab, tid); else build_hi_uv(Wc, wslab, tid);
    }
    __syncthreads();

    // ---- squared norms for layer 0 ----
    {
        bf16x8 hv = *(const bf16x8*)(fbhi + row1*KP + c0i);
        bf16x8 lv = *(const bf16x8*)(fblo + row1*KP + c0i);
        float s = 0.f;
        #pragma unroll
        for (int j = 0; j < 8; ++j){
            float vv = bf_u(hv[j]) + bf_u(lv[j]);
            s += vv*vv;
        }
        s += __shfl_xor(s, 1, 64);
        s += __shfl_xor(s, 2, 64);
        s += __shfl_xor(s, 4, 64);
        s += __shfl_xor(s, 8, 64);
        if ((tid & 15) == 0) sq[row1] = s;
    }
    __syncthreads();

    const short* Uhi = wslab;
    const short* Vhi = wslab + HSLAB;

    // ==== 3 EdgeConv layers (3 barriers each) ====
    for (int layer = 0; layer < 3; ++layer){
        // -- P1 (all-MFMA): dist (3-pass) + fused UV GEMM (1-pass A-hi), shared A-frags --
        f32x4 uA = {0,0,0,0}, uB = {0,0,0,0}, vA = {0,0,0,0}, vB = {0,0,0,0};
        {
            f32x4 dc = {0.f, 0.f, 0.f, 0.f};
            const int tm0 = wv >> 2, tn0d = wv & 3;
            const int arow = tm0*16 + (lane & 15);
            const int rB   = tn0d*16 + (lane & 15);
            const int ko   = (lane >> 4) * 8;
            #pragma unroll
            for (int ks = 0; ks < 4; ++ks){
                bf16x8 ah = *(const bf16x8*)(fbhi + arow*KP + ks*32 + ko);
                bf16x8 al = *(const bf16x8*)(fblo + arow*KP + ks*32 + ko);
                bf16x8 bh = *(const bf16x8*)(fbhi + rB*KP + ks*32 + ko);
                bf16x8 bl = *(const bf16x8*)(fblo + rB*KP + ks*32 + ko);
                dc = __builtin_amdgcn_mfma_f32_16x16x32_bf16(ah, bh, dc, 0,0,0);
                dc = __builtin_amdgcn_mfma_f32_16x16x32_bf16(ah, bl, dc, 0,0,0);
                dc = __builtin_amdgcn_mfma_f32_16x16x32_bf16(al, bh, dc, 0,0,0);
                const int f0 = (gtn0*4 + ks)*FRAG + lane*8;
                const int f1 = (gtn1*4 + ks)*FRAG + lane*8;
                bf16x8 bu0 = *(const bf16x8*)(Uhi + f0);
                bf16x8 bu1 = *(const bf16x8*)(Uhi + f1);
                bf16x8 bv0 = *(const bf16x8*)(Vhi + f0);
                bf16x8 bv1 = *(const bf16x8*)(Vhi + f1);
                uA = __builtin_amdgcn_mfma_f32_16x16x32_bf16(ah, bu0, uA, 0,0,0);
                uB = __builtin_amdgcn_mfma_f32_16x16x32_bf16(ah, bu1, uB, 0,0,0);
                vA = __builtin_amdgcn_mfma_f32_16x16x32_bf16(ah, bv0, vA, 0,0,0);
                vB = __builtin_amdgcn_mfma_f32_16x16x32_bf16(ah, bv1, vB, 0,0,0);
            }
            #pragma unroll
            for (int e = 0; e < 4; ++e){
                const int ra = tm0*16 + (lane >> 4)*4 + e, ca = tn0d*16 + (lane & 15);
                dmt[ra*DP + ca] = sq[ra] + sq[ca] - 2.f*dc[e];
            }
        }
        __syncthreads();

        // -- P2: write U(bf16 hi) -> fbhi, V(f16 pair-interleaved) -> Vbuf16;
        //        then kNN via streamed rank counting (byte offsets) --
        {
            #pragma unroll
            for (int half = 0; half < 2; ++half){
                const int tn  = half ? gtn1 : gtn0;
                const f32x4 cv = half ? vB : vA;
                const f32x4 cu = half ? uB : uA;
                const int col = tn*16 + (lane & 15);
                const int pc  = ((col & 63) << 1) + (col >> 6);   // interleaved position
                const int rb  = gtm*16 + (lane >> 4)*4;
                #pragma unroll
                for (int e = 0; e < 4; ++e){
                    Vbuf16[(rb + e)*VP + pc] = f2h(cv[e]);
                    fbhi[(rb + e)*KP + col] = bf_t(cu[e]);   // U stored hi-only
                }
            }
            #pragma unroll
            for (int p = 0; p < 4; ++p){
                const int r = wv*4 + p;
                const float dm = dmt[r*DP + lane];
                int rank = 0;
                #pragma unroll 4
                for (int q = 0; q < 16; ++q){
                    float4 v = *(const float4*)(dmt + r*DP + q*4);
                    rank += (v.x < dm) + (v.y < dm) + (v.z < dm) + (v.w < dm);
                }
                const unsigned long long mask = __ballot(rank < KK);
                if (rank < KK){
                    const int c = __popcll(mask & ((1ULL << lane) - 1ULL));
                    if (c < KK) knn[r*KK + c] = lane * (VP*2);   // byte offset
                }
            }
        }
        __syncthreads();

        // -- P3: combine via packed-f16 max; layers 0,1: write-back + sq;
        //        layer 2: fused pooling partials (features are dead after this) --
        {
            const int* kr = knn + row1*KK;
            int4 j0 = *(const int4*)(kr);
            int4 j1 = *(const int4*)(kr + 4);
            int4 j2 = *(const int4*)(kr + 8);
            int4 j3 = *(const int4*)(kr + 12);
            int4 j4 = *(const int4*)(kr + 16);
            int4 j5 = *(const int4*)(kr + 20);
            const char* Vb = (const char*)Vbuf16 + ((tid & 15) << 4);   // 16B per 4-col pair group
            unsigned mx0 = 0xFC00FC00u, mx1 = 0xFC00FC00u, mx2 = 0xFC00FC00u, mx3 = 0xFC00FC00u;
            #define GM(J) { \
                uint4 v = *(const uint4*)(Vb + (J)); \
                mx0 = pkmax(mx0, v.x); mx1 = pkmax(mx1, v.y); \
                mx2 = pkmax(mx2, v.z); mx3 = pkmax(mx3, v.w); }
            GM(j0.x) GM(j0.y) GM(j0.z) GM(j0.w)
            GM(j1.x) GM(j1.y) GM(j1.z) GM(j1.w)
            GM(j2.x) GM(j2.y) GM(j2.z) GM(j2.w)
            GM(j3.x) GM(j3.y) GM(j3.z) GM(j3.w)
            GM(j4.x) GM(j4.y) GM(j4.z) GM(j4.w)
            GM(j5.x) GM(j5.y) GM(j5.z) GM(j5.w)
            #undef GM
            float2 m0 = h22f2(mx0), m1 = h22f2(mx1), m2 = h22f2(mx2), m3 = h22f2(mx3);
            uint4 sv = *(const uint4*)(Vb + row1*(VP*2));
            float2 s0 = h22f2(sv.x), s1 = h22f2(sv.y), s2 = h22f2(sv.z), s3 = h22f2(sv.w);
            float4 bcA = *(const float4*)(bc + c2);
            float4 bcB = *(const float4*)(bc + c2 + 64);
            short4 uhA = *(const short4*)(fbhi + row1*KP + c2);
            short4 uhB = *(const short4*)(fbhi + row1*KP + c2 + 64);
            float o0 = elu1(bf_u(uhA.x) - s0.x + bcA.x + m0.x);
            float o1 = elu1(bf_u(uhA.y) - s1.x + bcA.y + m1.x);
            float o2 = elu1(bf_u(uhA.z) - s2.x + bcA.z + m2.x);
            float o3 = elu1(bf_u(uhA.w) - s3.x + bcA.w + m3.x);
            float o4 = elu1(bf_u(uhB.x) - s0.y + bcB.x + m0.y);
            float o5 = elu1(bf_u(uhB.y) - s1.y + bcB.y + m1.y);
            float o6 = elu1(bf_u(uhB.z) - s2.y + bcB.z + m2.y);
            float o7 = elu1(bf_u(uhB.w) - s3.y + bcB.w + m3.y);
            if (layer < 2){
                short4 nhA, nlA, nhB, nlB;
                nhA.x = bf_t(o0); nlA.x = bf_t(o0 - bf_u(nhA.x));
                nhA.y = bf_t(o1); nlA.y = bf_t(o1 - bf_u(nhA.y));
                nhA.z = bf_t(o2); nlA.z = bf_t(o2 - bf_u(nhA.z));
                nhA.w = bf_t(o3); nlA.w = bf_t(o3 - bf_u(nhA.w));
                nhB.x = bf_t(o4); nlB.x = bf_t(o4 - bf_u(nhB.x));
                nhB.y = bf_t(o5); nlB.y = bf_t(o5 - bf_u(nhB.y));
                nhB.z = bf_t(o6); nlB.z = bf_t(o6 - bf_u(nhB.z));
                nhB.w = bf_t(o7); nlB.w = bf_t(o7 - bf_u(nhB.w));
                *(short4*)(fbhi + row1*KP + c2)      = nhA;
                *(short4*)(fbhi + row1*KP + c2 + 64) = nhB;
                *(short4*)(fblo + row1*KP + c2)      = nlA;
                *(short4*)(fblo + row1*KP + c2 + 64) = nlB;
                float s = o0*o0 + o1*o1 + o2*o2 + o3*o3 + o4*o4 + o5*o5 + o6*o6 + o7*o7;
                s += __shfl_xor(s, 1, 64);
                s += __shfl_xor(s, 2, 64);
                s += __shfl_xor(s, 4, 64);
                s += __shfl_xor(s, 8, 64);
                if ((tid & 15) == 0) sq[row1] = s;
            } else {
                // fused pooling: sum the wave's 4 rows in-register (lanes ±16, ±32 share cg)
                o0 += __shfl_xor(o0, 16, 64); o0 += __shfl_xor(o0, 32, 64);
                o1 += __shfl_xor(o1, 16, 64); o1 += __shfl_xor(o1, 32, 64);
                o2 += __shfl_xor(o2, 16, 64); o2 += __shfl_xor(o2, 32, 64);
                o3 += __shfl_xor(o3, 16, 64); o3 += __shfl_xor(o3, 32, 64);
                o4 += __shfl_xor(o4, 16, 64); o4 += __shfl_xor(o4, 32, 64);
                o5 += __shfl_xor(o5, 16, 64); o5 += __shfl_xor(o5, 32, 64);
                o6 += __shfl_xor(o6, 16, 64); o6 += __shfl_xor(o6, 32, 64);
                o7 += __shfl_xor(o7, 16, 64); o7 += __shfl_xor(o7, 32, 64);
                if (lane < 16){
                    float* red = dmt + 128;   // dmt dead (kNN done); 16 partials x 128 ch
                    *(float4*)(red + wv*HID + c2)      = make_float4(o0, o1, o2, o3);
                    *(float4*)(red + wv*HID + c2 + 64) = make_float4(o4, o5, o6, o7);
                }
            }
        }
        __syncthreads();
    }

    // ==== reduce 16 pooling partials -> pooled; then head (scratch in dmt) ====
    float* pooled = dmt;             // 128
    float* redp   = dmt + 128;       // 16x128 partials (written above), then head scratch
    float* hr1    = dmt + 2176;      // 64
    float* hr2    = dmt + 2240;      // 32
    float* hr3    = dmt + 2272;      // 32

    if (tid < HID){
        float s = 0.f;
        #pragma unroll
        for (int p = 0; p < 16; ++p) s += redp[p*HID + tid];
        pooled[tid] = s;
    }
    __syncthreads();
    if (tid < 256){
        const int o = tid & 63, part = tid >> 6;
        float s = 0.f;
        for (int f = part*32; f < part*32 + 32; ++f) s += pooled[f] * Wo1[f*64 + o];
        redp[part*64 + o] = s;
    }
    __syncthreads();
    if (tid < 64) hr1[tid] = elu1(bo1[tid] + redp[tid] + redp[64+tid] + redp[128+tid] + redp[192+tid]);
    __syncthreads();
    if (tid < 128){
        const int o = tid & 31, part = tid >> 5;
        float s = 0.f;
        for (int f = part*16; f < part*16 + 16; ++f) s += hr1[f] * Wo2[f*32 + o];
        redp[part*32 + o] = s;
    }
    __syncthreads();
    if (tid < 32) hr2[tid] = elu1(bo2[tid] + redp[tid] + redp[32+tid] + redp[64+tid] + redp[96+tid]);
    __syncthreads();
    if (tid < 32){
        float a = bo3[tid];
        for (int f = 0; f < 32; ++f) a += hr2[f] * Wo3[f*32 + tid];
        hr3[tid] = elu1(a);
    }
    __syncthreads();
    if (tid < 8){
        float a = bo4[tid];
        for (int f = 0; f < 32; ++f) a += hr3[f] * Wo4[f*8 + tid];
        out[g*8 + tid] = a;
    }
}

extern "C" void kernel_launch(void* const* d_in, const int* in_sizes, int n_in,
                              void* d_out, int out_size, void* d_ws, size_t ws_size,
                              hipStream_t stream) {
    short* img = (short*)d_ws;
    const int use_img = (ws_size >= (size_t)IMG_BYTES) ? 1 : 0;
    if (use_img) {
        const int total = 3*8*4*64;   // 6144 threads
        prep_kernel<<<(total + 255)/256, 256, 0, stream>>>(
            (const float*)d_in[4], (const float*)d_in[6], img);
    }
    dgcnn_kernel<<<NG, 1024, 0, stream>>>(
        (const float*)d_in[0],
        (const float*)d_in[2],  (const float*)d_in[3],
        (const float*)d_in[4],  (const float*)d_in[5],
        (const float*)d_in[6],  (const float*)d_in[7],
        (const float*)d_in[8],  (const float*)d_in[9],
        (const float*)d_in[10], (const float*)d_in[11],
        (const float*)d_in[12], (const float*)d_in[13],
        (const float*)d_in[14], (const float*)d_in[15],
        img, use_img,
        (float*)d_out);
}